// Round 11
// baseline (1056.149 us; speedup 1.0000x reference)
//
#include <hip/hip_runtime.h>
#include <math.h>
#include <stdint.h>

#define Bsz 8
#define Lsz 8192
#define D 256
#define NROWS (Bsz*Lsz)      // 65536
#define NC 128               // chunks per sequence
#define CL (Lsz/NC)          // 64
#define LN_EPS 1e-6f

typedef float f32x4 __attribute__((ext_vector_type(4)));
typedef short bf16x8 __attribute__((ext_vector_type(8)));

__device__ __forceinline__ float gelu_tanh(float v){
    const float k0 = 0.7978845608028654f;   // sqrt(2/pi)
    const float k1 = 0.044715f;
    float inner = k0 * fmaf(k1*v*v, v, v);
    return 0.5f * v * (1.0f + tanhf(inner));
}
__device__ __forceinline__ uint16_t bf16_rne(float f){
    uint32_t u = __float_as_uint(f);
    return (uint16_t)((u + 0x7fffu + ((u>>16)&1u)) >> 16);
}
__device__ __forceinline__ float bf16_to_f(uint16_t h){
    return __uint_as_float(((uint32_t)h)<<16);
}

// frag-major short index: 16B chunk = (row-tile, k-chunk), lane-row inside.
__device__ __forceinline__ int frag_s(int row, int k, int KC){
    return ((row>>4)*KC + (k>>3))*128 + (row&15)*8 + (k&7);
}
// bu/h plane DWORD index == frag_s(row, 2h, 64)/2 -> scan packs IN PLACE.
__device__ __forceinline__ int bu_dw(int row, int h){
    return ((row>>4)*64 + (h>>2))*64 + (row&15)*4 + (h&3);
}

// ---- prep: split weights to bf16 hi/lo planes, frag-major ------------------
__global__ __launch_bounds__(256)
void k_prep(const float* __restrict__ B_re, const float* __restrict__ B_im,
            const float* __restrict__ C_re, const float* __restrict__ C_im,
            const float* __restrict__ W, const float* __restrict__ ln_scale,
            short* __restrict__ b1_hi, short* __restrict__ b1_lo,
            short* __restrict__ b2_hi, short* __restrict__ b2_lo,
            short* __restrict__ b3_hi, short* __restrict__ b3_lo){
    int i = blockIdx.x*256 + threadIdx.x;   // 131072
    {   // b1 [512 n][256 k]
        int n = i >> 8, d = i & 255;
        float v = (n < 256 ? B_re[n*256 + d] : B_im[(n-256)*256 + d]) * ln_scale[d];
        uint16_t hi = bf16_rne(v);
        int o = frag_s(n, d, 32);
        b1_hi[o] = (short)hi;
        b1_lo[o] = (short)bf16_rne(v - bf16_to_f(hi));
    }
    {   // b2 [256 n][512 k], K-interleaved re/im
        int n = i >> 9, k = i & 511, h = k >> 1;
        float v = (k & 1) ? -C_im[n*256 + h] : C_re[n*256 + h];
        uint16_t hi = bf16_rne(v);
        int o = frag_s(n, k, 64);
        b2_hi[o] = (short)hi;
        b2_lo[o] = (short)bf16_rne(v - bf16_to_f(hi));
    }
    if (i < 256*256){   // b3 [256 n][256 k]
        int n = i >> 8, d = i & 255;
        float v = W[i];
        uint16_t hi = bf16_rne(v);
        int o = frag_s(n, d, 32);
        b3_hi[o] = (short)hi;
        b3_lo[o] = (short)bf16_rne(v - bf16_to_f(hi));
    }
}

__global__ __launch_bounds__(256)
void k_prep_t(const float* __restrict__ B_re, const float* __restrict__ B_im,
              const float* __restrict__ ln_scale, const float* __restrict__ ln_bias,
              float* __restrict__ t1, float* __restrict__ t2){
    int n = blockIdx.x*256 + threadIdx.x;
    if (n >= 512) return;
    const float* src = (n < 256) ? &B_re[n*256] : &B_im[(n-256)*256];
    float s1 = 0.f, s2 = 0.f;
    for (int d = 0; d < 256; d++){
        float b = src[d];
        s1 = fmaf(ln_scale[d], b, s1);
        s2 = fmaf(ln_bias[d],  b, s2);
    }
    t1[n] = s1; t2[n] = s2;
}

// ---- stats: LN (mu, rstd) + xhi/xlo planes (frag-major K=256) --------------
__global__ __launch_bounds__(256)
void k_stats(const float* __restrict__ x, float* __restrict__ mu_arr,
             float* __restrict__ rstd_arr, short* __restrict__ xhi,
             short* __restrict__ xlo){
    int r0 = blockIdx.x * 16;
    int t = threadIdx.x;
    int wave = t >> 6, lane = t & 63;
    for (int rr = wave; rr < 16; rr += 4){
        int row = r0 + rr;
        const float* xr = x + (size_t)row * D;
        float v[4]; float s = 0.f;
        #pragma unroll
        for (int i=0;i<4;i++){ v[i] = xr[lane + 64*i]; s += v[i]; }
        #pragma unroll
        for (int off=32; off; off>>=1) s += __shfl_xor(s, off);
        float mu = s * (1.0f/D);
        float vs = 0.f;
        #pragma unroll
        for (int i=0;i<4;i++){ float dd = v[i]-mu; vs += dd*dd; }
        #pragma unroll
        for (int off=32; off; off>>=1) vs += __shfl_xor(vs, off);
        float rstd = rsqrtf(vs*(1.0f/D) + LN_EPS);
        if (lane == 0){ mu_arr[row] = mu; rstd_arr[row] = rstd; }
        #pragma unroll
        for (int i=0;i<4;i++){
            int dd = lane + 64*i;
            uint16_t hb = bf16_rne(v[i]);
            int o = frag_s(row, dd, 32);
            xhi[o] = (short)hb;
            xlo[o] = (short)bf16_rne(v[i] - bf16_to_f(hb));
        }
    }
}

// ---- LDS-free register GEMM, 2-deep pipeline, 4 blocks/CU ------------------
// 256 thr = 4 waves (2x2), block tile 128x128, wave tile 64x64, split-bf16
// 3-product. r10 showed the compiler re-serializes the frag sets to ~108 VGPR
// and gets 16% MfmaUtil at 2 blocks/CU; since VGPR<=128 and LDS=0, raise
// residency to 4 blocks/CU (16 waves/CU) -> 4 waves/SIMD x ~240cy MFMA per
// K-step covers the ~900cy cold-load latency via TLP.
template<int MODE>
__global__ __launch_bounds__(256, 4)
void k_gemm(const short* __restrict__ Ahi_g, const short* __restrict__ Alo_g,
            const short* __restrict__ Bhi_g, const short* __restrict__ Blo_g,
            const float* __restrict__ x,
            const float* __restrict__ mu_arr, const float* __restrict__ rs_arr,
            const float* __restrict__ t1, const float* __restrict__ t2,
            const float* __restrict__ nu_log,
            const float* __restrict__ ln_scale, const float* __restrict__ ln_bias,
            const float* __restrict__ d_skip, const float* __restrict__ bvec,
            float* __restrict__ outA, float* __restrict__ outB,
            short* __restrict__ gh, short* __restrict__ gl){
    constexpr int K   = (MODE==2) ? 512 : 256;
    constexpr int KC  = K/8;
    constexpr int KCS = KC*128;                   // shorts per row-tile plane
    constexpr int NYB = (MODE==1) ? 4 : 2;
    constexpr int NT  = K/32;
    const int nwg = (int)gridDim.x;               // multiple of 8
    const int bid = ((int)blockIdx.x & 7)*(nwg>>3) + ((int)blockIdx.x >> 3);
    const int wv = threadIdx.x >> 6, lane = threadIdx.x & 63;
    const int lgrp = lane >> 4, lrow = lane & 15;
    const int rt0 = (bid/NYB)*8 + (wv>>1)*4;      // wave A row-tile base
    const int nt0 = (bid%NYB)*8 + (wv&1)*4;       // wave B row-tile base
    const int abase = (rt0*KC + lgrp)*128 + lrow*8;
    const int bbase = (nt0*KC + lgrp)*128 + lrow*8;

    f32x4 acc[4][4];
    #pragma unroll
    for (int mf=0;mf<4;mf++)
    #pragma unroll
    for (int nf=0;nf<4;nf++) acc[mf][nf] = (f32x4){0.f,0.f,0.f,0.f};

    bf16x8 fa0h[4], fa0l[4], fb0h[4], fb0l[4];
    bf16x8 fa1h[4], fa1l[4], fb1h[4], fb1l[4];

#define LDSET(S, KT) do{ const int ko_ = (KT)*512; \
    _Pragma("unroll") \
    for (int nf=0;nf<4;nf++){ \
        fb##S##h[nf] = *(const bf16x8*)&Bhi_g[bbase + nf*KCS + ko_]; \
        fb##S##l[nf] = *(const bf16x8*)&Blo_g[bbase + nf*KCS + ko_]; } \
    _Pragma("unroll") \
    for (int mf=0;mf<4;mf++){ \
        fa##S##h[mf] = *(const bf16x8*)&Ahi_g[abase + mf*KCS + ko_]; \
        fa##S##l[mf] = *(const bf16x8*)&Alo_g[abase + mf*KCS + ko_]; } \
}while(0)

#define MMSET(S) do{ \
    _Pragma("unroll") \
    for (int mf=0;mf<4;mf++) \
    _Pragma("unroll") \
    for (int nf=0;nf<4;nf++){ \
        acc[mf][nf] = __builtin_amdgcn_mfma_f32_16x16x32_bf16(fa##S##h[mf], fb##S##h[nf], acc[mf][nf],0,0,0); \
        acc[mf][nf] = __builtin_amdgcn_mfma_f32_16x16x32_bf16(fa##S##h[mf], fb##S##l[nf], acc[mf][nf],0,0,0); \
        acc[mf][nf] = __builtin_amdgcn_mfma_f32_16x16x32_bf16(fa##S##l[mf], fb##S##h[nf], acc[mf][nf],0,0,0); } \
}while(0)

    LDSET(0, 0);
    #pragma unroll 1
    for (int kt = 0; kt < NT; kt += 2){
        LDSET(1, kt+1);              // issue next tile's 16 loads
        MMSET(0);                    // compiler waits only set0 (counted)
        if (kt+2 < NT) LDSET(0, kt+2);
        MMSET(1);
    }
#undef LDSET
#undef MMSET

    // ---- epilogue ----
    const int mrow0 = (bid/NYB)*128 + (wv>>1)*64;
    const int col0  = (bid%NYB)*128 + (wv&1)*64;
    #pragma unroll
    for (int nf=0; nf<4; nf++){
        const int col = col0 + nf*16 + lrow;      // MODE1: 0..511 else 0..255
        if (MODE == 1){
            float gam = sqrtf(1.0f - expf(-2.0f*expf(nu_log[col & 255])));
            float t1v = t1[col], t2v = t2[col];
            float* dst = (col < 256) ? outA : outB;
            int c2 = col & 255;
            #pragma unroll
            for (int mf=0;mf<4;mf++){
                #pragma unroll
                for (int j=0;j<4;j++){
                    int row = mrow0 + mf*16 + lgrp*4 + j;
                    float rs = rs_arr[row], muv = mu_arr[row];
                    dst[bu_dw(row, c2)] = gam * (rs*acc[mf][nf][j] - rs*muv*t1v + t2v);
                }
            }
        } else if (MODE == 2){
            float dsk = d_skip[col], sc = ln_scale[col], bi = ln_bias[col];
            #pragma unroll
            for (int mf=0;mf<4;mf++){
                #pragma unroll
                for (int j=0;j<4;j++){
                    int row = mrow0 + mf*16 + lgrp*4 + j;
                    size_t idx = (size_t)row*256 + col;
                    float rs = rs_arr[row], muv = mu_arr[row];
                    float xn = (x[idx] - muv)*rs*sc + bi;
                    float g = gelu_tanh(acc[mf][nf][j] + dsk*xn);
                    uint16_t hb = bf16_rne(g);
                    int o = frag_s(row, col, 32);
                    gh[o] = (short)hb;
                    gl[o] = (short)bf16_rne(g - bf16_to_f(hb));
                }
            }
        } else {
            float bb = bvec[col];
            #pragma unroll
            for (int mf=0;mf<4;mf++){
                #pragma unroll
                for (int j=0;j<4;j++){
                    int row = mrow0 + mf*16 + lgrp*4 + j;
                    size_t idx = (size_t)row*256 + col;
                    outA[idx] = acc[mf][nf][j] + bb + x[idx];
                }
            }
        }
    }
}

// ---- scan kernels (bu planes in bu_dw layout) -------------------------------
__global__ __launch_bounds__(256)
void k_scan_local(const float* __restrict__ nu_log, const float* __restrict__ theta_log,
                  const float* __restrict__ bu_re, const float* __restrict__ bu_im,
                  float* __restrict__ e_re, float* __restrict__ e_im){
    int h = threadIdx.x;
    int bc = blockIdx.x;
    int b = bc / NC, c = bc % NC;
    float en = expf(nu_log[h]);
    float mag = expf(-en), th = expf(theta_log[h]);
    float lam_re = mag * cosf(th), lam_im = mag * sinf(th);
    int row0 = b*Lsz + c*CL;
    float sr = 0.f, si = 0.f;
    #pragma unroll 4
    for (int tt=0; tt<CL; tt++){
        int o = bu_dw(row0 + tt, h);
        float ur = bu_re[o], ui = bu_im[o];
        float nsr = fmaf(lam_re, sr, fmaf(-lam_im, si, ur));
        float nsi = fmaf(lam_re, si, fmaf( lam_im, sr, ui));
        sr = nsr; si = nsi;
    }
    e_re[(c*Bsz + b)*D + h] = sr;
    e_im[(c*Bsz + b)*D + h] = si;
}

__global__ __launch_bounds__(256)
void k_scan_combine(const float* __restrict__ nu_log, const float* __restrict__ theta_log,
                    const float* __restrict__ e_re, const float* __restrict__ e_im,
                    float* __restrict__ p_re, float* __restrict__ p_im){
    int h = threadIdx.x;
    int b = blockIdx.x;
    double en = exp((double)nu_log[h]);
    double th = exp((double)theta_log[h]);
    double mag = exp(-en);
    double lr = mag*cos(th), li = mag*sin(th);
    double ar = 1.0, ai = 0.0;               // lam^CL
    for (int i=0;i<CL;i++){
        double nr = ar*lr - ai*li;
        double ni = ar*li + ai*lr;
        ar = nr; ai = ni;
    }
    double sr = 0.0, si = 0.0;
    for (int c=0;c<NC;c++){
        int idx = (c*Bsz + b)*D + h;
        p_re[idx] = (float)sr; p_im[idx] = (float)si;
        double er = e_re[idx], ei = e_im[idx];
        double nr = ar*sr - ai*si + er;
        double ni = ar*si + ai*sr + ei;
        sr = nr; si = ni;
    }
}

// re-scan with prefix; pack h IN PLACE (same dwords) -> frag-major K=512.
__global__ __launch_bounds__(256)
void k_scan_apply(const float* __restrict__ nu_log, const float* __restrict__ theta_log,
                  const float* __restrict__ p_re, const float* __restrict__ p_im,
                  float* __restrict__ bu_re, float* __restrict__ bu_im){
    int h = threadIdx.x;
    int bc = blockIdx.x;
    int b = bc / NC, c = bc % NC;
    float en = expf(nu_log[h]);
    float mag = expf(-en), th = expf(theta_log[h]);
    float lam_re = mag * cosf(th), lam_im = mag * sinf(th);
    int pidx = (c*Bsz + b)*D + h;
    float sr = p_re[pidx], si = p_im[pidx];
    int row0 = b*Lsz + c*CL;
    #pragma unroll 4
    for (int tt=0; tt<CL; tt++){
        int o = bu_dw(row0 + tt, h);
        float ur = bu_re[o], ui = bu_im[o];
        float nsr = fmaf(lam_re, sr, fmaf(-lam_im, si, ur));
        float nsi = fmaf(lam_re, si, fmaf( lam_im, sr, ui));
        sr = nsr; si = nsi;
        uint16_t rh = bf16_rne(sr), ih = bf16_rne(si);
        uint16_t rl = bf16_rne(sr - bf16_to_f(rh));
        uint16_t il = bf16_rne(si - bf16_to_f(ih));
        ((uint32_t*)bu_re)[o] = (uint32_t)rh | ((uint32_t)ih << 16);
        ((uint32_t*)bu_im)[o] = (uint32_t)rl | ((uint32_t)il << 16);
    }
}

extern "C" void kernel_launch(void* const* d_in, const int* in_sizes, int n_in,
                              void* d_out, int out_size, void* d_ws, size_t ws_size,
                              hipStream_t stream){
    const float* x         = (const float*)d_in[0];
    const float* ln_scale  = (const float*)d_in[1];
    const float* ln_bias   = (const float*)d_in[2];
    const float* nu_log    = (const float*)d_in[3];
    const float* theta_log = (const float*)d_in[4];
    const float* B_re      = (const float*)d_in[5];
    const float* B_im      = (const float*)d_in[6];
    const float* C_re      = (const float*)d_in[7];
    const float* C_im      = (const float*)d_in[8];
    const float* D_skip    = (const float*)d_in[9];
    const float* W         = (const float*)d_in[10];
    const float* bvec      = (const float*)d_in[11];
    float* out = (float*)d_out;

    char* base = (char*)d_ws;
    size_t off = 0;
    auto alloc = [&](size_t bytes)->char*{
        char* p = base + off;
        off += (bytes + 255) & ~(size_t)255;
        return p;
    };
    float*  bu_re = (float*)alloc((size_t)NROWS*D*4);   // later: h hi-plane
    float*  bu_im = (float*)alloc((size_t)NROWS*D*4);   // later: h lo-plane
    short*  xg_hi = (short*)alloc((size_t)NROWS*D*2);   // xhi, later ghi
    short*  xg_lo = (short*)alloc((size_t)NROWS*D*2);   // xlo, later glo
    float*  mu_a  = (float*)alloc((size_t)NROWS*4);
    float*  rs_a  = (float*)alloc((size_t)NROWS*4);
    float*  e_re  = (float*)alloc((size_t)NC*Bsz*D*4);
    float*  e_im  = (float*)alloc((size_t)NC*Bsz*D*4);
    float*  p_re  = (float*)alloc((size_t)NC*Bsz*D*4);
    float*  p_im  = (float*)alloc((size_t)NC*Bsz*D*4);
    float*  t1    = (float*)alloc(512*4);
    float*  t2    = (float*)alloc(512*4);
    short*  b1_hi = (short*)alloc(512*256*2);
    short*  b1_lo = (short*)alloc(512*256*2);
    short*  b2_hi = (short*)alloc(256*512*2);
    short*  b2_lo = (short*)alloc(256*512*2);
    short*  b3_hi = (short*)alloc(256*256*2);
    short*  b3_lo = (short*)alloc(256*256*2);

    k_prep<<<512, 256, 0, stream>>>(B_re, B_im, C_re, C_im, W, ln_scale,
                                    b1_hi, b1_lo, b2_hi, b2_lo, b3_hi, b3_lo);
    k_prep_t<<<2, 256, 0, stream>>>(B_re, B_im, ln_scale, ln_bias, t1, t2);
    k_stats<<<NROWS/16, 256, 0, stream>>>(x, mu_a, rs_a, xg_hi, xg_lo);

    // GEMM1: Bu = gamma*(LN(x) @ B1^T)   (N=512: cols 0-255 re, 256-511 im)
    k_gemm<1><<<(NROWS/128)*4, 256, 0, stream>>>(
        xg_hi, xg_lo, b1_hi, b1_lo, x, mu_a, rs_a, t1, t2, nu_log,
        ln_scale, ln_bias, D_skip, bvec, bu_re, bu_im, nullptr, nullptr);

    k_scan_local<<<Bsz*NC, 256, 0, stream>>>(nu_log, theta_log, bu_re, bu_im, e_re, e_im);
    k_scan_combine<<<Bsz, 256, 0, stream>>>(nu_log, theta_log, e_re, e_im, p_re, p_im);
    k_scan_apply<<<Bsz*NC, 256, 0, stream>>>(nu_log, theta_log, p_re, p_im, bu_re, bu_im);

    // GEMM2: y = Re(h C^T) + Dskip*xn -> gelu -> g planes (alias x-planes)
    k_gemm<2><<<(NROWS/128)*2, 256, 0, stream>>>(
        (const short*)bu_re, (const short*)bu_im, b2_hi, b2_lo, x,
        mu_a, rs_a, t1, t2, nu_log, ln_scale, ln_bias, D_skip, bvec,
        nullptr, nullptr, xg_hi, xg_lo);

    // GEMM3: out = g W^T + b + x
    k_gemm<3><<<(NROWS/128)*2, 256, 0, stream>>>(
        xg_hi, xg_lo, b3_hi, b3_lo, x, mu_a, rs_a, t1, t2, nu_log,
        ln_scale, ln_bias, D_skip, bvec, out, nullptr, nullptr, nullptr);
}

// Round 14
// 389.620 us; speedup vs baseline: 2.7107x; 2.7107x over previous
//
#include <hip/hip_runtime.h>
#include <math.h>
#include <stdint.h>

#define Bsz 8
#define Lsz 8192
#define D 256
#define NROWS (Bsz*Lsz)      // 65536
#define NC 128               // chunks per sequence
#define CL (Lsz/NC)          // 64
#define LN_EPS 1e-6f

typedef float f32x4 __attribute__((ext_vector_type(4)));
typedef short bf16x8 __attribute__((ext_vector_type(8)));

__device__ __forceinline__ float gelu_tanh(float v){
    const float k0 = 0.7978845608028654f;   // sqrt(2/pi)
    const float k1 = 0.044715f;
    float inner = k0 * fmaf(k1*v*v, v, v);
    return 0.5f * v * (1.0f + tanhf(inner));
}
__device__ __forceinline__ uint16_t bf16_rne(float f){
    uint32_t u = __float_as_uint(f);
    return (uint16_t)((u + 0x7fffu + ((u>>16)&1u)) >> 16);
}
__device__ __forceinline__ float bf16_to_f(uint16_t h){
    return __uint_as_float(((uint32_t)h)<<16);
}

// frag-major short index: 16B chunk = (row-tile, k-chunk), lane-row inside.
__device__ __forceinline__ int frag_s(int row, int k, int KC){
    return ((row>>4)*KC + (k>>3))*128 + (row&15)*8 + (k&7);
}
// bu/h plane DWORD index == frag_s(row, 2h, 64)/2 -> scan packs IN PLACE.
__device__ __forceinline__ int bu_dw(int row, int h){
    return ((row>>4)*64 + (h>>2))*64 + (row&15)*4 + (h&3);
}

// ---- prep: split weights to bf16 hi/lo planes, frag-major ------------------
__global__ __launch_bounds__(256)
void k_prep(const float* __restrict__ B_re, const float* __restrict__ B_im,
            const float* __restrict__ C_re, const float* __restrict__ C_im,
            const float* __restrict__ W, const float* __restrict__ ln_scale,
            short* __restrict__ b1_hi, short* __restrict__ b1_lo,
            short* __restrict__ b2_hi, short* __restrict__ b2_lo,
            short* __restrict__ b3_hi, short* __restrict__ b3_lo){
    int i = blockIdx.x*256 + threadIdx.x;   // 131072
    {   // b1 [512 n][256 k]
        int n = i >> 8, d = i & 255;
        float v = (n < 256 ? B_re[n*256 + d] : B_im[(n-256)*256 + d]) * ln_scale[d];
        uint16_t hi = bf16_rne(v);
        int o = frag_s(n, d, 32);
        b1_hi[o] = (short)hi;
        b1_lo[o] = (short)bf16_rne(v - bf16_to_f(hi));
    }
    {   // b2 [256 n][512 k], K-interleaved re/im
        int n = i >> 9, k = i & 511, h = k >> 1;
        float v = (k & 1) ? -C_im[n*256 + h] : C_re[n*256 + h];
        uint16_t hi = bf16_rne(v);
        int o = frag_s(n, k, 64);
        b2_hi[o] = (short)hi;
        b2_lo[o] = (short)bf16_rne(v - bf16_to_f(hi));
    }
    if (i < 256*256){   // b3 [256 n][256 k]
        int n = i >> 8, d = i & 255;
        float v = W[i];
        uint16_t hi = bf16_rne(v);
        int o = frag_s(n, d, 32);
        b3_hi[o] = (short)hi;
        b3_lo[o] = (short)bf16_rne(v - bf16_to_f(hi));
    }
}

__global__ __launch_bounds__(256)
void k_prep_t(const float* __restrict__ B_re, const float* __restrict__ B_im,
              const float* __restrict__ ln_scale, const float* __restrict__ ln_bias,
              float* __restrict__ t1, float* __restrict__ t2){
    int n = blockIdx.x*256 + threadIdx.x;
    if (n >= 512) return;
    const float* src = (n < 256) ? &B_re[n*256] : &B_im[(n-256)*256];
    float s1 = 0.f, s2 = 0.f;
    for (int d = 0; d < 256; d++){
        float b = src[d];
        s1 = fmaf(ln_scale[d], b, s1);
        s2 = fmaf(ln_bias[d],  b, s2);
    }
    t1[n] = s1; t2[n] = s2;
}

// ---- stats: LN (mu, rstd) + xhi/xlo planes (frag-major K=256) --------------
__global__ __launch_bounds__(256)
void k_stats(const float* __restrict__ x, float* __restrict__ mu_arr,
             float* __restrict__ rstd_arr, short* __restrict__ xhi,
             short* __restrict__ xlo){
    int r0 = blockIdx.x * 16;
    int t = threadIdx.x;
    int wave = t >> 6, lane = t & 63;
    for (int rr = wave; rr < 16; rr += 4){
        int row = r0 + rr;
        const float* xr = x + (size_t)row * D;
        float v[4]; float s = 0.f;
        #pragma unroll
        for (int i=0;i<4;i++){ v[i] = xr[lane + 64*i]; s += v[i]; }
        #pragma unroll
        for (int off=32; off; off>>=1) s += __shfl_xor(s, off);
        float mu = s * (1.0f/D);
        float vs = 0.f;
        #pragma unroll
        for (int i=0;i<4;i++){ float dd = v[i]-mu; vs += dd*dd; }
        #pragma unroll
        for (int off=32; off; off>>=1) vs += __shfl_xor(vs, off);
        float rstd = rsqrtf(vs*(1.0f/D) + LN_EPS);
        if (lane == 0){ mu_arr[row] = mu; rstd_arr[row] = rstd; }
        #pragma unroll
        for (int i=0;i<4;i++){
            int dd = lane + 64*i;
            uint16_t hb = bf16_rne(v[i]);
            int o = frag_s(row, dd, 32);
            xhi[o] = (short)hb;
            xlo[o] = (short)bf16_rne(v[i] - bf16_to_f(hb));
        }
    }
}

// ---- LDS-free register GEMM, sched_barrier-pinned 2-deep pipeline ----------
// 256 thr = 4 waves (2x2), block tile 128x128, wave tile 64x64, split-bf16
// 3-product. sched_barrier(0) after each LDSET forbids the scheduler from
// sinking prefetch loads below the current MFMA block -> both frag sets live
// (~210 VGPR), counted vmcnt waits, issue-to-use = one 48-MFMA block.
template<int MODE>
__global__ __launch_bounds__(256, 2)
void k_gemm(const short* __restrict__ Ahi_g, const short* __restrict__ Alo_g,
            const short* __restrict__ Bhi_g, const short* __restrict__ Blo_g,
            const float* __restrict__ x,
            const float* __restrict__ mu_arr, const float* __restrict__ rs_arr,
            const float* __restrict__ t1, const float* __restrict__ t2,
            const float* __restrict__ nu_log,
            const float* __restrict__ ln_scale, const float* __restrict__ ln_bias,
            const float* __restrict__ d_skip, const float* __restrict__ bvec,
            float* __restrict__ outA, float* __restrict__ outB,
            short* __restrict__ gh, short* __restrict__ gl){
    constexpr int K   = (MODE==2) ? 512 : 256;
    constexpr int KC  = K/8;
    constexpr int KCS = KC*128;                   // shorts per row-tile plane
    constexpr int NYB = (MODE==1) ? 4 : 2;
    constexpr int NT  = K/32;
    const int nwg = (int)gridDim.x;               // multiple of 8
    const int bid = ((int)blockIdx.x & 7)*(nwg>>3) + ((int)blockIdx.x >> 3);
    const int wv = threadIdx.x >> 6, lane = threadIdx.x & 63;
    const int lgrp = lane >> 4, lrow = lane & 15;
    const int rt0 = (bid/NYB)*8 + (wv>>1)*4;      // wave A row-tile base
    const int nt0 = (bid%NYB)*8 + (wv&1)*4;       // wave B row-tile base
    const int abase = (rt0*KC + lgrp)*128 + lrow*8;
    const int bbase = (nt0*KC + lgrp)*128 + lrow*8;

    f32x4 acc[4][4];
    #pragma unroll
    for (int mf=0;mf<4;mf++)
    #pragma unroll
    for (int nf=0;nf<4;nf++) acc[mf][nf] = (f32x4){0.f,0.f,0.f,0.f};

    bf16x8 fa0h[4], fa0l[4], fb0h[4], fb0l[4];
    bf16x8 fa1h[4], fa1l[4], fb1h[4], fb1l[4];

#define LDSET(S, KT) do{ const int ko_ = (KT)*512; \
    _Pragma("unroll") \
    for (int nf=0;nf<4;nf++){ \
        fb##S##h[nf] = *(const bf16x8*)&Bhi_g[bbase + nf*KCS + ko_]; \
        fb##S##l[nf] = *(const bf16x8*)&Blo_g[bbase + nf*KCS + ko_]; } \
    _Pragma("unroll") \
    for (int mf=0;mf<4;mf++){ \
        fa##S##h[mf] = *(const bf16x8*)&Ahi_g[abase + mf*KCS + ko_]; \
        fa##S##l[mf] = *(const bf16x8*)&Alo_g[abase + mf*KCS + ko_]; } \
}while(0)

#define MMSET(S) do{ \
    _Pragma("unroll") \
    for (int mf=0;mf<4;mf++) \
    _Pragma("unroll") \
    for (int nf=0;nf<4;nf++){ \
        acc[mf][nf] = __builtin_amdgcn_mfma_f32_16x16x32_bf16(fa##S##h[mf], fb##S##h[nf], acc[mf][nf],0,0,0); \
        acc[mf][nf] = __builtin_amdgcn_mfma_f32_16x16x32_bf16(fa##S##h[mf], fb##S##l[nf], acc[mf][nf],0,0,0); \
        acc[mf][nf] = __builtin_amdgcn_mfma_f32_16x16x32_bf16(fa##S##l[mf], fb##S##h[nf], acc[mf][nf],0,0,0); } \
}while(0)

    LDSET(0, 0);
    #pragma unroll 1
    for (int kt = 0; kt < NT; kt += 2){
        LDSET(1, kt+1);                          // issue next tile's 16 loads
        __builtin_amdgcn_sched_barrier(0);       // pin: loads above, MFMAs below
        MMSET(0);                                // counted vmcnt waits set0 only
        if (kt+2 < NT) LDSET(0, kt+2);
        __builtin_amdgcn_sched_barrier(0);
        MMSET(1);
    }
#undef LDSET
#undef MMSET

    // ---- epilogue ----
    const int mrow0 = (bid/NYB)*128 + (wv>>1)*64;
    const int col0  = (bid%NYB)*128 + (wv&1)*64;
    #pragma unroll
    for (int nf=0; nf<4; nf++){
        const int col = col0 + nf*16 + lrow;      // MODE1: 0..511 else 0..255
        if (MODE == 1){
            float gam = sqrtf(1.0f - expf(-2.0f*expf(nu_log[col & 255])));
            float t1v = t1[col], t2v = t2[col];
            float* dst = (col < 256) ? outA : outB;
            int c2 = col & 255;
            #pragma unroll
            for (int mf=0;mf<4;mf++){
                #pragma unroll
                for (int j=0;j<4;j++){
                    int row = mrow0 + mf*16 + lgrp*4 + j;
                    float rs = rs_arr[row], muv = mu_arr[row];
                    dst[bu_dw(row, c2)] = gam * (rs*acc[mf][nf][j] - rs*muv*t1v + t2v);
                }
            }
        } else if (MODE == 2){
            float dsk = d_skip[col], sc = ln_scale[col], bi = ln_bias[col];
            #pragma unroll
            for (int mf=0;mf<4;mf++){
                #pragma unroll
                for (int j=0;j<4;j++){
                    int row = mrow0 + mf*16 + lgrp*4 + j;
                    size_t idx = (size_t)row*256 + col;
                    float rs = rs_arr[row], muv = mu_arr[row];
                    float xn = (x[idx] - muv)*rs*sc + bi;
                    float g = gelu_tanh(acc[mf][nf][j] + dsk*xn);
                    uint16_t hb = bf16_rne(g);
                    int o = frag_s(row, col, 32);
                    gh[o] = (short)hb;
                    gl[o] = (short)bf16_rne(g - bf16_to_f(hb));
                }
            }
        } else {
            float bb = bvec[col];
            #pragma unroll
            for (int mf=0;mf<4;mf++){
                #pragma unroll
                for (int j=0;j<4;j++){
                    int row = mrow0 + mf*16 + lgrp*4 + j;
                    size_t idx = (size_t)row*256 + col;
                    outA[idx] = acc[mf][nf][j] + bb + x[idx];
                }
            }
        }
    }
}

// ---- scan kernels (bu planes in bu_dw layout) -------------------------------
__global__ __launch_bounds__(256)
void k_scan_local(const float* __restrict__ nu_log, const float* __restrict__ theta_log,
                  const float* __restrict__ bu_re, const float* __restrict__ bu_im,
                  float* __restrict__ e_re, float* __restrict__ e_im){
    int h = threadIdx.x;
    int bc = blockIdx.x;
    int b = bc / NC, c = bc % NC;
    float en = expf(nu_log[h]);
    float mag = expf(-en), th = expf(theta_log[h]);
    float lam_re = mag * cosf(th), lam_im = mag * sinf(th);
    int row0 = b*Lsz + c*CL;
    float sr = 0.f, si = 0.f;
    #pragma unroll 4
    for (int tt=0; tt<CL; tt++){
        int o = bu_dw(row0 + tt, h);
        float ur = bu_re[o], ui = bu_im[o];
        float nsr = fmaf(lam_re, sr, fmaf(-lam_im, si, ur));
        float nsi = fmaf(lam_re, si, fmaf( lam_im, sr, ui));
        sr = nsr; si = nsi;
    }
    e_re[(c*Bsz + b)*D + h] = sr;
    e_im[(c*Bsz + b)*D + h] = si;
}

__global__ __launch_bounds__(256)
void k_scan_combine(const float* __restrict__ nu_log, const float* __restrict__ theta_log,
                    const float* __restrict__ e_re, const float* __restrict__ e_im,
                    float* __restrict__ p_re, float* __restrict__ p_im){
    int h = threadIdx.x;
    int b = blockIdx.x;
    double en = exp((double)nu_log[h]);
    double th = exp((double)theta_log[h]);
    double mag = exp(-en);
    double lr = mag*cos(th), li = mag*sin(th);
    double ar = 1.0, ai = 0.0;               // lam^CL
    for (int i=0;i<CL;i++){
        double nr = ar*lr - ai*li;
        double ni = ar*li + ai*lr;
        ar = nr; ai = ni;
    }
    double sr = 0.0, si = 0.0;
    for (int c=0;c<NC;c++){
        int idx = (c*Bsz + b)*D + h;
        p_re[idx] = (float)sr; p_im[idx] = (float)si;
        double er = e_re[idx], ei = e_im[idx];
        double nr = ar*sr - ai*si + er;
        double ni = ar*si + ai*sr + ei;
        sr = nr; si = ni;
    }
}

// re-scan with prefix; pack h IN PLACE (same dwords) -> frag-major K=512.
__global__ __launch_bounds__(256)
void k_scan_apply(const float* __restrict__ nu_log, const float* __restrict__ theta_log,
                  const float* __restrict__ p_re, const float* __restrict__ p_im,
                  float* __restrict__ bu_re, float* __restrict__ bu_im){
    int h = threadIdx.x;
    int bc = blockIdx.x;
    int b = bc / NC, c = bc % NC;
    float en = expf(nu_log[h]);
    float mag = expf(-en), th = expf(theta_log[h]);
    float lam_re = mag * cosf(th), lam_im = mag * sinf(th);
    int pidx = (c*Bsz + b)*D + h;
    float sr = p_re[pidx], si = p_im[pidx];
    int row0 = b*Lsz + c*CL;
    #pragma unroll 4
    for (int tt=0; tt<CL; tt++){
        int o = bu_dw(row0 + tt, h);
        float ur = bu_re[o], ui = bu_im[o];
        float nsr = fmaf(lam_re, sr, fmaf(-lam_im, si, ur));
        float nsi = fmaf(lam_re, si, fmaf( lam_im, sr, ui));
        sr = nsr; si = nsi;
        uint16_t rh = bf16_rne(sr), ih = bf16_rne(si);
        uint16_t rl = bf16_rne(sr - bf16_to_f(rh));
        uint16_t il = bf16_rne(si - bf16_to_f(ih));
        ((uint32_t*)bu_re)[o] = (uint32_t)rh | ((uint32_t)ih << 16);
        ((uint32_t*)bu_im)[o] = (uint32_t)rl | ((uint32_t)il << 16);
    }
}

extern "C" void kernel_launch(void* const* d_in, const int* in_sizes, int n_in,
                              void* d_out, int out_size, void* d_ws, size_t ws_size,
                              hipStream_t stream){
    const float* x         = (const float*)d_in[0];
    const float* ln_scale  = (const float*)d_in[1];
    const float* ln_bias   = (const float*)d_in[2];
    const float* nu_log    = (const float*)d_in[3];
    const float* theta_log = (const float*)d_in[4];
    const float* B_re      = (const float*)d_in[5];
    const float* B_im      = (const float*)d_in[6];
    const float* C_re      = (const float*)d_in[7];
    const float* C_im      = (const float*)d_in[8];
    const float* D_skip    = (const float*)d_in[9];
    const float* W         = (const float*)d_in[10];
    const float* bvec      = (const float*)d_in[11];
    float* out = (float*)d_out;

    char* base = (char*)d_ws;
    size_t off = 0;
    auto alloc = [&](size_t bytes)->char*{
        char* p = base + off;
        off += (bytes + 255) & ~(size_t)255;
        return p;
    };
    float*  bu_re = (float*)alloc((size_t)NROWS*D*4);   // later: h hi-plane
    float*  bu_im = (float*)alloc((size_t)NROWS*D*4);   // later: h lo-plane
    short*  xg_hi = (short*)alloc((size_t)NROWS*D*2);   // xhi, later ghi
    short*  xg_lo = (short*)alloc((size_t)NROWS*D*2);   // xlo, later glo
    float*  mu_a  = (float*)alloc((size_t)NROWS*4);
    float*  rs_a  = (float*)alloc((size_t)NROWS*4);
    float*  e_re  = (float*)alloc((size_t)NC*Bsz*D*4);
    float*  e_im  = (float*)alloc((size_t)NC*Bsz*D*4);
    float*  p_re  = (float*)alloc((size_t)NC*Bsz*D*4);
    float*  p_im  = (float*)alloc((size_t)NC*Bsz*D*4);
    float*  t1    = (float*)alloc(512*4);
    float*  t2    = (float*)alloc(512*4);
    short*  b1_hi = (short*)alloc(512*256*2);
    short*  b1_lo = (short*)alloc(512*256*2);
    short*  b2_hi = (short*)alloc(256*512*2);
    short*  b2_lo = (short*)alloc(256*512*2);
    short*  b3_hi = (short*)alloc(256*256*2);
    short*  b3_lo = (short*)alloc(256*256*2);

    k_prep<<<512, 256, 0, stream>>>(B_re, B_im, C_re, C_im, W, ln_scale,
                                    b1_hi, b1_lo, b2_hi, b2_lo, b3_hi, b3_lo);
    k_prep_t<<<2, 256, 0, stream>>>(B_re, B_im, ln_scale, ln_bias, t1, t2);
    k_stats<<<NROWS/16, 256, 0, stream>>>(x, mu_a, rs_a, xg_hi, xg_lo);

    // GEMM1: Bu = gamma*(LN(x) @ B1^T)   (N=512: cols 0-255 re, 256-511 im)
    k_gemm<1><<<(NROWS/128)*4, 256, 0, stream>>>(
        xg_hi, xg_lo, b1_hi, b1_lo, x, mu_a, rs_a, t1, t2, nu_log,
        ln_scale, ln_bias, D_skip, bvec, bu_re, bu_im, nullptr, nullptr);

    k_scan_local<<<Bsz*NC, 256, 0, stream>>>(nu_log, theta_log, bu_re, bu_im, e_re, e_im);
    k_scan_combine<<<Bsz, 256, 0, stream>>>(nu_log, theta_log, e_re, e_im, p_re, p_im);
    k_scan_apply<<<Bsz*NC, 256, 0, stream>>>(nu_log, theta_log, p_re, p_im, bu_re, bu_im);

    // GEMM2: y = Re(h C^T) + Dskip*xn -> gelu -> g planes (alias x-planes)
    k_gemm<2><<<(NROWS/128)*2, 256, 0, stream>>>(
        (const short*)bu_re, (const short*)bu_im, b2_hi, b2_lo, x,
        mu_a, rs_a, t1, t2, nu_log, ln_scale, ln_bias, D_skip, bvec,
        nullptr, nullptr, xg_hi, xg_lo);

    // GEMM3: out = g W^T + b + x
    k_gemm<3><<<(NROWS/128)*2, 256, 0, stream>>>(
        xg_hi, xg_lo, b3_hi, b3_lo, x, mu_a, rs_a, t1, t2, nu_log,
        ln_scale, ln_bias, D_skip, bvec, out, nullptr, nullptr, nullptr);
}

// Round 16
// 372.182 us; speedup vs baseline: 2.8377x; 1.0469x over previous
//
#include <hip/hip_runtime.h>
#include <math.h>
#include <stdint.h>

#define Bsz 8
#define Lsz 8192
#define D 256
#define NROWS (Bsz*Lsz)      // 65536
#define NC 128               // chunks per sequence
#define CL (Lsz/NC)          // 64
#define LN_EPS 1e-6f

typedef float f32x4 __attribute__((ext_vector_type(4)));
typedef short bf16x8 __attribute__((ext_vector_type(8)));

__device__ __forceinline__ float gelu_tanh(float v){
    const float k0 = 0.7978845608028654f;   // sqrt(2/pi)
    const float k1 = 0.044715f;
    float inner = k0 * fmaf(k1*v*v, v, v);
    return 0.5f * v * (1.0f + tanhf(inner));
}
__device__ __forceinline__ uint16_t bf16_rne(float f){
    uint32_t u = __float_as_uint(f);
    return (uint16_t)((u + 0x7fffu + ((u>>16)&1u)) >> 16);
}
__device__ __forceinline__ float bf16_to_f(uint16_t h){
    return __uint_as_float(((uint32_t)h)<<16);
}

// frag-major short index: 16B chunk = (row-tile, k-chunk), lane-row inside.
__device__ __forceinline__ int frag_s(int row, int k, int KC){
    return ((row>>4)*KC + (k>>3))*128 + (row&15)*8 + (k&7);
}
// bu/h plane DWORD index == frag_s(row, 2h, 64)/2 -> scan packs IN PLACE.
__device__ __forceinline__ int bu_dw(int row, int h){
    return ((row>>4)*64 + (h>>2))*64 + (row&15)*4 + (h&3);
}

// ---- prep: split weights to bf16 hi/lo planes, frag-major ------------------
__global__ __launch_bounds__(256)
void k_prep(const float* __restrict__ B_re, const float* __restrict__ B_im,
            const float* __restrict__ C_re, const float* __restrict__ C_im,
            const float* __restrict__ W, const float* __restrict__ ln_scale,
            short* __restrict__ b1_hi, short* __restrict__ b1_lo,
            short* __restrict__ b2_hi, short* __restrict__ b2_lo,
            short* __restrict__ b3_hi, short* __restrict__ b3_lo){
    int i = blockIdx.x*256 + threadIdx.x;   // 131072
    {   // b1 [512 n][256 k]
        int n = i >> 8, d = i & 255;
        float v = (n < 256 ? B_re[n*256 + d] : B_im[(n-256)*256 + d]) * ln_scale[d];
        uint16_t hi = bf16_rne(v);
        int o = frag_s(n, d, 32);
        b1_hi[o] = (short)hi;
        b1_lo[o] = (short)bf16_rne(v - bf16_to_f(hi));
    }
    {   // b2 [256 n][512 k], K-interleaved re/im
        int n = i >> 9, k = i & 511, h = k >> 1;
        float v = (k & 1) ? -C_im[n*256 + h] : C_re[n*256 + h];
        uint16_t hi = bf16_rne(v);
        int o = frag_s(n, k, 64);
        b2_hi[o] = (short)hi;
        b2_lo[o] = (short)bf16_rne(v - bf16_to_f(hi));
    }
    if (i < 256*256){   // b3 [256 n][256 k]
        int n = i >> 8, d = i & 255;
        float v = W[i];
        uint16_t hi = bf16_rne(v);
        int o = frag_s(n, d, 32);
        b3_hi[o] = (short)hi;
        b3_lo[o] = (short)bf16_rne(v - bf16_to_f(hi));
    }
}

__global__ __launch_bounds__(256)
void k_prep_t(const float* __restrict__ B_re, const float* __restrict__ B_im,
              const float* __restrict__ ln_scale, const float* __restrict__ ln_bias,
              float* __restrict__ t1, float* __restrict__ t2){
    int n = blockIdx.x*256 + threadIdx.x;
    if (n >= 512) return;
    const float* src = (n < 256) ? &B_re[n*256] : &B_im[(n-256)*256];
    float s1 = 0.f, s2 = 0.f;
    for (int d = 0; d < 256; d++){
        float b = src[d];
        s1 = fmaf(ln_scale[d], b, s1);
        s2 = fmaf(ln_bias[d],  b, s2);
    }
    t1[n] = s1; t2[n] = s2;
}

// ---- stats: LN (mu, rstd) + xhi/xlo planes (frag-major K=256) --------------
__global__ __launch_bounds__(256)
void k_stats(const float* __restrict__ x, float* __restrict__ mu_arr,
             float* __restrict__ rstd_arr, short* __restrict__ xhi,
             short* __restrict__ xlo){
    int r0 = blockIdx.x * 16;
    int t = threadIdx.x;
    int wave = t >> 6, lane = t & 63;
    for (int rr = wave; rr < 16; rr += 4){
        int row = r0 + rr;
        const float* xr = x + (size_t)row * D;
        float v[4]; float s = 0.f;
        #pragma unroll
        for (int i=0;i<4;i++){ v[i] = xr[lane + 64*i]; s += v[i]; }
        #pragma unroll
        for (int off=32; off; off>>=1) s += __shfl_xor(s, off);
        float mu = s * (1.0f/D);
        float vs = 0.f;
        #pragma unroll
        for (int i=0;i<4;i++){ float dd = v[i]-mu; vs += dd*dd; }
        #pragma unroll
        for (int off=32; off; off>>=1) vs += __shfl_xor(vs, off);
        float rstd = rsqrtf(vs*(1.0f/D) + LN_EPS);
        if (lane == 0){ mu_arr[row] = mu; rstd_arr[row] = rstd; }
        #pragma unroll
        for (int i=0;i<4;i++){
            int dd = lane + 64*i;
            uint16_t hb = bf16_rne(v[i]);
            int o = frag_s(row, dd, 32);
            xhi[o] = (short)hb;
            xlo[o] = (short)bf16_rne(v[i] - bf16_to_f(hb));
        }
    }
}

// ---- GEMM1 (r10-proven): LDS-free register GEMM, 2-deep pipeline ------------
// 256 thr = 4 waves (2x2), block 128x128, wave 64x64, split-bf16 3-product.
__global__ __launch_bounds__(256, 2)
void k_gemm1(const short* __restrict__ Ahi_g, const short* __restrict__ Alo_g,
             const short* __restrict__ Bhi_g, const short* __restrict__ Blo_g,
             const float* __restrict__ mu_arr, const float* __restrict__ rs_arr,
             const float* __restrict__ t1, const float* __restrict__ t2,
             const float* __restrict__ nu_log,
             float* __restrict__ outA, float* __restrict__ outB){
    constexpr int K = 256, KC = K/8, KCS = KC*128, NYB = 4, NT = K/32;
    const int nwg = (int)gridDim.x;               // multiple of 8
    const int bid = ((int)blockIdx.x & 7)*(nwg>>3) + ((int)blockIdx.x >> 3);
    const int wv = threadIdx.x >> 6, lane = threadIdx.x & 63;
    const int lgrp = lane >> 4, lrow = lane & 15;
    const int rt0 = (bid/NYB)*8 + (wv>>1)*4;
    const int nt0 = (bid%NYB)*8 + (wv&1)*4;
    const int abase = (rt0*KC + lgrp)*128 + lrow*8;
    const int bbase = (nt0*KC + lgrp)*128 + lrow*8;

    f32x4 acc[4][4];
    #pragma unroll
    for (int mf=0;mf<4;mf++)
    #pragma unroll
    for (int nf=0;nf<4;nf++) acc[mf][nf] = (f32x4){0.f,0.f,0.f,0.f};

    bf16x8 fa0h[4], fa0l[4], fb0h[4], fb0l[4];
    bf16x8 fa1h[4], fa1l[4], fb1h[4], fb1l[4];

#define LDSET(S, KT) do{ const int ko_ = (KT)*512; \
    _Pragma("unroll") \
    for (int nf=0;nf<4;nf++){ \
        fb##S##h[nf] = *(const bf16x8*)&Bhi_g[bbase + nf*KCS + ko_]; \
        fb##S##l[nf] = *(const bf16x8*)&Blo_g[bbase + nf*KCS + ko_]; } \
    _Pragma("unroll") \
    for (int mf=0;mf<4;mf++){ \
        fa##S##h[mf] = *(const bf16x8*)&Ahi_g[abase + mf*KCS + ko_]; \
        fa##S##l[mf] = *(const bf16x8*)&Alo_g[abase + mf*KCS + ko_]; } \
}while(0)

#define MMSET(S) do{ \
    _Pragma("unroll") \
    for (int mf=0;mf<4;mf++) \
    _Pragma("unroll") \
    for (int nf=0;nf<4;nf++){ \
        acc[mf][nf] = __builtin_amdgcn_mfma_f32_16x16x32_bf16(fa##S##h[mf], fb##S##h[nf], acc[mf][nf],0,0,0); \
        acc[mf][nf] = __builtin_amdgcn_mfma_f32_16x16x32_bf16(fa##S##h[mf], fb##S##l[nf], acc[mf][nf],0,0,0); \
        acc[mf][nf] = __builtin_amdgcn_mfma_f32_16x16x32_bf16(fa##S##l[mf], fb##S##h[nf], acc[mf][nf],0,0,0); } \
}while(0)

    LDSET(0, 0);
    #pragma unroll 1
    for (int kt = 0; kt < NT; kt += 2){
        LDSET(1, kt+1);
        MMSET(0);
        if (kt+2 < NT) LDSET(0, kt+2);
        MMSET(1);
    }
#undef LDSET
#undef MMSET

    const int mrow0 = (bid/NYB)*128 + (wv>>1)*64;
    const int col0  = (bid%NYB)*128 + (wv&1)*64;
    #pragma unroll
    for (int nf=0; nf<4; nf++){
        const int col = col0 + nf*16 + lrow;      // 0..511
        float gam = sqrtf(1.0f - expf(-2.0f*expf(nu_log[col & 255])));
        float t1v = t1[col], t2v = t2[col];
        float* dst = (col < 256) ? outA : outB;
        int c2 = col & 255;
        #pragma unroll
        for (int mf=0;mf<4;mf++){
            #pragma unroll
            for (int j=0;j<4;j++){
                int row = mrow0 + mf*16 + lgrp*4 + j;
                float rs = rs_arr[row], muv = mu_arr[row];
                dst[bu_dw(row, c2)] = gam * (rs*acc[mf][nf][j] - rs*muv*t1v + t2v);
            }
        }
    }
}

// ---- fused GEMM2+GEMM3: 64 rows x 256 cols, g staged through LDS -----------
// 4 waves, wave wv owns cols wv*64..+63 for BOTH stages, rows all 64.
// Stage1: y = h(.)C^T + Dskip*xn (K=512, h planes) -> gelu -> g hi/lo to LDS
// (frag-major KC=32, conflict-free). Stage2: out = g W^T + b + x (K=256,
// A-frags from LDS ds_read_b128, B3 from global/L2).
__global__ __launch_bounds__(256, 2)
void k_fuse23(const short* __restrict__ Ahi_g, const short* __restrict__ Alo_g,
              const short* __restrict__ B2hi, const short* __restrict__ B2lo,
              const short* __restrict__ B3hi, const short* __restrict__ B3lo,
              const float* __restrict__ x,
              const float* __restrict__ mu_arr, const float* __restrict__ rs_arr,
              const float* __restrict__ ln_scale, const float* __restrict__ ln_bias,
              const float* __restrict__ d_skip, const float* __restrict__ bvec,
              float* __restrict__ out){
    constexpr int K1 = 512, KC1 = K1/8, KCS1 = KC1*128, NT1 = K1/32;
    constexpr int KCS3 = 32*128, NT2 = 8;         // stage2: K=256, KC=32
    __shared__ __align__(16) short Gh[64*256];    // 32 KB
    __shared__ __align__(16) short Gl[64*256];    // 32 KB
    const int bid = blockIdx.x;                   // 1024 blocks, 64 rows each
    const int wv = threadIdx.x >> 6, lane = threadIdx.x & 63;
    const int lgrp = lane >> 4, lrow = lane & 15;
    const int r0 = bid*64;
    const int abase = ((bid*4)*KC1 + lgrp)*128 + lrow*8;   // A row-tiles bid*4+mf
    const int bbase = ((wv*4)*KC1 + lgrp)*128 + lrow*8;    // B2 n-tiles wv*4+nf

    f32x4 acc[4][4];
    #pragma unroll
    for (int mf=0;mf<4;mf++)
    #pragma unroll
    for (int nf=0;nf<4;nf++) acc[mf][nf] = (f32x4){0.f,0.f,0.f,0.f};

    bf16x8 fa0h[4], fa0l[4], fb0h[4], fb0l[4];
    bf16x8 fa1h[4], fa1l[4], fb1h[4], fb1l[4];

#define LDSET(S, KT) do{ const int ko_ = (KT)*512; \
    _Pragma("unroll") \
    for (int nf=0;nf<4;nf++){ \
        fb##S##h[nf] = *(const bf16x8*)&B2hi[bbase + nf*KCS1 + ko_]; \
        fb##S##l[nf] = *(const bf16x8*)&B2lo[bbase + nf*KCS1 + ko_]; } \
    _Pragma("unroll") \
    for (int mf=0;mf<4;mf++){ \
        fa##S##h[mf] = *(const bf16x8*)&Ahi_g[abase + mf*KCS1 + ko_]; \
        fa##S##l[mf] = *(const bf16x8*)&Alo_g[abase + mf*KCS1 + ko_]; } \
}while(0)

#define MMSET(S) do{ \
    _Pragma("unroll") \
    for (int mf=0;mf<4;mf++) \
    _Pragma("unroll") \
    for (int nf=0;nf<4;nf++){ \
        acc[mf][nf] = __builtin_amdgcn_mfma_f32_16x16x32_bf16(fa##S##h[mf], fb##S##h[nf], acc[mf][nf],0,0,0); \
        acc[mf][nf] = __builtin_amdgcn_mfma_f32_16x16x32_bf16(fa##S##h[mf], fb##S##l[nf], acc[mf][nf],0,0,0); \
        acc[mf][nf] = __builtin_amdgcn_mfma_f32_16x16x32_bf16(fa##S##l[mf], fb##S##h[nf], acc[mf][nf],0,0,0); } \
}while(0)

    LDSET(0, 0);
    #pragma unroll 1
    for (int kt = 0; kt < NT1; kt += 2){
        LDSET(1, kt+1);
        MMSET(0);
        if (kt+2 < NT1) LDSET(0, kt+2);
        MMSET(1);
    }
#undef LDSET
#undef MMSET

    // ---- epilogue 1: gelu(y + Dskip*xn) -> LDS (frag-major, KC=32) ----
    #pragma unroll
    for (int nf=0; nf<4; nf++){
        const int col = wv*64 + nf*16 + lrow;     // 0..255
        float dsk = d_skip[col], sc = ln_scale[col], bi = ln_bias[col];
        #pragma unroll
        for (int mf=0;mf<4;mf++){
            #pragma unroll
            for (int j=0;j<4;j++){
                int rl = mf*16 + lgrp*4 + j;      // local row 0..63
                int row = r0 + rl;
                size_t idx = (size_t)row*256 + col;
                float rs = rs_arr[row], muv = mu_arr[row];
                float xn = (x[idx] - muv)*rs*sc + bi;
                float g = gelu_tanh(acc[mf][nf][j] + dsk*xn);
                uint16_t hb = bf16_rne(g);
                int o = (mf*32 + (col>>3))*128 + (lgrp*4+j)*8 + (col&7);
                Gh[o] = (short)hb;
                Gl[o] = (short)bf16_rne(g - bf16_to_f(hb));
            }
        }
    }
    __syncthreads();

    // ---- stage 2: out = g W^T + b + x ----
    #pragma unroll
    for (int mf=0;mf<4;mf++)
    #pragma unroll
    for (int nf=0;nf<4;nf++) acc[mf][nf] = (f32x4){0.f,0.f,0.f,0.f};

    const int b3base = ((wv*4)*32 + lgrp)*128 + lrow*8;
    #pragma unroll 1
    for (int kt = 0; kt < NT2; ++kt){
        const int ko = kt*512;
        bf16x8 bh[4], bl[4], ah[4], al[4];
        #pragma unroll
        for (int nf=0;nf<4;nf++){
            bh[nf] = *(const bf16x8*)&B3hi[b3base + nf*KCS3 + ko];
            bl[nf] = *(const bf16x8*)&B3lo[b3base + nf*KCS3 + ko];
        }
        #pragma unroll
        for (int mf=0;mf<4;mf++){
            const int o = (mf*32 + kt*4 + lgrp)*128 + lrow*8;
            ah[mf] = *(const bf16x8*)&Gh[o];
            al[mf] = *(const bf16x8*)&Gl[o];
        }
        #pragma unroll
        for (int mf=0;mf<4;mf++)
        #pragma unroll
        for (int nf=0;nf<4;nf++){
            acc[mf][nf] = __builtin_amdgcn_mfma_f32_16x16x32_bf16(ah[mf], bh[nf], acc[mf][nf],0,0,0);
            acc[mf][nf] = __builtin_amdgcn_mfma_f32_16x16x32_bf16(ah[mf], bl[nf], acc[mf][nf],0,0,0);
            acc[mf][nf] = __builtin_amdgcn_mfma_f32_16x16x32_bf16(al[mf], bh[nf], acc[mf][nf],0,0,0);
        }
    }

    #pragma unroll
    for (int nf=0; nf<4; nf++){
        const int col = wv*64 + nf*16 + lrow;
        float bb = bvec[col];
        #pragma unroll
        for (int mf=0;mf<4;mf++){
            #pragma unroll
            for (int j=0;j<4;j++){
                int row = r0 + mf*16 + lgrp*4 + j;
                size_t idx = (size_t)row*256 + col;
                out[idx] = acc[mf][nf][j] + bb + x[idx];
            }
        }
    }
}

// ---- scan kernels (bu planes in bu_dw layout) -------------------------------
__global__ __launch_bounds__(256)
void k_scan_local(const float* __restrict__ nu_log, const float* __restrict__ theta_log,
                  const float* __restrict__ bu_re, const float* __restrict__ bu_im,
                  float* __restrict__ e_re, float* __restrict__ e_im){
    int h = threadIdx.x;
    int bc = blockIdx.x;
    int b = bc / NC, c = bc % NC;
    float en = expf(nu_log[h]);
    float mag = expf(-en), th = expf(theta_log[h]);
    float lam_re = mag * cosf(th), lam_im = mag * sinf(th);
    int row0 = b*Lsz + c*CL;
    float sr = 0.f, si = 0.f;
    #pragma unroll 4
    for (int tt=0; tt<CL; tt++){
        int o = bu_dw(row0 + tt, h);
        float ur = bu_re[o], ui = bu_im[o];
        float nsr = fmaf(lam_re, sr, fmaf(-lam_im, si, ur));
        float nsi = fmaf(lam_re, si, fmaf( lam_im, sr, ui));
        sr = nsr; si = nsi;
    }
    e_re[(c*Bsz + b)*D + h] = sr;
    e_im[(c*Bsz + b)*D + h] = si;
}

__global__ __launch_bounds__(256)
void k_scan_combine(const float* __restrict__ nu_log, const float* __restrict__ theta_log,
                    const float* __restrict__ e_re, const float* __restrict__ e_im,
                    float* __restrict__ p_re, float* __restrict__ p_im){
    int h = threadIdx.x;
    int b = blockIdx.x;
    double en = exp((double)nu_log[h]);
    double th = exp((double)theta_log[h]);
    double mag = exp(-en);
    double lr = mag*cos(th), li = mag*sin(th);
    double ar = 1.0, ai = 0.0;               // lam^CL
    for (int i=0;i<CL;i++){
        double nr = ar*lr - ai*li;
        double ni = ar*li + ai*lr;
        ar = nr; ai = ni;
    }
    double sr = 0.0, si = 0.0;
    for (int c=0;c<NC;c++){
        int idx = (c*Bsz + b)*D + h;
        p_re[idx] = (float)sr; p_im[idx] = (float)si;
        double er = e_re[idx], ei = e_im[idx];
        double nr = ar*sr - ai*si + er;
        double ni = ar*si + ai*sr + ei;
        sr = nr; si = ni;
    }
}

// re-scan with prefix; pack h IN PLACE (same dwords) -> frag-major K=512.
__global__ __launch_bounds__(256)
void k_scan_apply(const float* __restrict__ nu_log, const float* __restrict__ theta_log,
                  const float* __restrict__ p_re, const float* __restrict__ p_im,
                  float* __restrict__ bu_re, float* __restrict__ bu_im){
    int h = threadIdx.x;
    int bc = blockIdx.x;
    int b = bc / NC, c = bc % NC;
    float en = expf(nu_log[h]);
    float mag = expf(-en), th = expf(theta_log[h]);
    float lam_re = mag * cosf(th), lam_im = mag * sinf(th);
    int pidx = (c*Bsz + b)*D + h;
    float sr = p_re[pidx], si = p_im[pidx];
    int row0 = b*Lsz + c*CL;
    #pragma unroll 4
    for (int tt=0; tt<CL; tt++){
        int o = bu_dw(row0 + tt, h);
        float ur = bu_re[o], ui = bu_im[o];
        float nsr = fmaf(lam_re, sr, fmaf(-lam_im, si, ur));
        float nsi = fmaf(lam_re, si, fmaf( lam_im, sr, ui));
        sr = nsr; si = nsi;
        uint16_t rh = bf16_rne(sr), ih = bf16_rne(si);
        uint16_t rl = bf16_rne(sr - bf16_to_f(rh));
        uint16_t il = bf16_rne(si - bf16_to_f(ih));
        ((uint32_t*)bu_re)[o] = (uint32_t)rh | ((uint32_t)ih << 16);
        ((uint32_t*)bu_im)[o] = (uint32_t)rl | ((uint32_t)il << 16);
    }
}

extern "C" void kernel_launch(void* const* d_in, const int* in_sizes, int n_in,
                              void* d_out, int out_size, void* d_ws, size_t ws_size,
                              hipStream_t stream){
    const float* x         = (const float*)d_in[0];
    const float* ln_scale  = (const float*)d_in[1];
    const float* ln_bias   = (const float*)d_in[2];
    const float* nu_log    = (const float*)d_in[3];
    const float* theta_log = (const float*)d_in[4];
    const float* B_re      = (const float*)d_in[5];
    const float* B_im      = (const float*)d_in[6];
    const float* C_re      = (const float*)d_in[7];
    const float* C_im      = (const float*)d_in[8];
    const float* D_skip    = (const float*)d_in[9];
    const float* W         = (const float*)d_in[10];
    const float* bvec      = (const float*)d_in[11];
    float* out = (float*)d_out;

    char* base = (char*)d_ws;
    size_t off = 0;
    auto alloc = [&](size_t bytes)->char*{
        char* p = base + off;
        off += (bytes + 255) & ~(size_t)255;
        return p;
    };
    float*  bu_re = (float*)alloc((size_t)NROWS*D*4);   // later: h hi-plane
    float*  bu_im = (float*)alloc((size_t)NROWS*D*4);   // later: h lo-plane
    short*  xg_hi = (short*)alloc((size_t)NROWS*D*2);   // xhi (GEMM1 A)
    short*  xg_lo = (short*)alloc((size_t)NROWS*D*2);   // xlo
    float*  mu_a  = (float*)alloc((size_t)NROWS*4);
    float*  rs_a  = (float*)alloc((size_t)NROWS*4);
    float*  e_re  = (float*)alloc((size_t)NC*Bsz*D*4);
    float*  e_im  = (float*)alloc((size_t)NC*Bsz*D*4);
    float*  p_re  = (float*)alloc((size_t)NC*Bsz*D*4);
    float*  p_im  = (float*)alloc((size_t)NC*Bsz*D*4);
    float*  t1    = (float*)alloc(512*4);
    float*  t2    = (float*)alloc(512*4);
    short*  b1_hi = (short*)alloc(512*256*2);
    short*  b1_lo = (short*)alloc(512*256*2);
    short*  b2_hi = (short*)alloc(256*512*2);
    short*  b2_lo = (short*)alloc(256*512*2);
    short*  b3_hi = (short*)alloc(256*256*2);
    short*  b3_lo = (short*)alloc(256*256*2);

    k_prep<<<512, 256, 0, stream>>>(B_re, B_im, C_re, C_im, W, ln_scale,
                                    b1_hi, b1_lo, b2_hi, b2_lo, b3_hi, b3_lo);
    k_prep_t<<<2, 256, 0, stream>>>(B_re, B_im, ln_scale, ln_bias, t1, t2);
    k_stats<<<NROWS/16, 256, 0, stream>>>(x, mu_a, rs_a, xg_hi, xg_lo);

    // GEMM1: Bu = gamma*(LN(x) @ B1^T)   (N=512: cols 0-255 re, 256-511 im)
    k_gemm1<<<(NROWS/128)*4, 256, 0, stream>>>(
        xg_hi, xg_lo, b1_hi, b1_lo, mu_a, rs_a, t1, t2, nu_log, bu_re, bu_im);

    k_scan_local<<<Bsz*NC, 256, 0, stream>>>(nu_log, theta_log, bu_re, bu_im, e_re, e_im);
    k_scan_combine<<<Bsz, 256, 0, stream>>>(nu_log, theta_log, e_re, e_im, p_re, p_im);
    k_scan_apply<<<Bsz*NC, 256, 0, stream>>>(nu_log, theta_log, p_re, p_im, bu_re, bu_im);

    // fused GEMM2+GEMM3: y -> gelu -> (LDS) -> out = g W^T + b + x
    k_fuse23<<<NROWS/64, 256, 0, stream>>>(
        (const short*)bu_re, (const short*)bu_im, b2_hi, b2_lo, b3_hi, b3_lo,
        x, mu_a, rs_a, ln_scale, ln_bias, D_skip, bvec, out);
}